// Round 1
// baseline (738.829 us; speedup 1.0000x reference)
//
#include <hip/hip_runtime.h>
#include <hip/hip_bf16.h>
#include <math.h>

#define BB 2
#define AA 120000
#define CC 80
#define K_PRE 500
#define MAX_DET 300
#define CAP 2048
#define NBINS 256
#define CHUNK 1024
#define NCHUNK ((AA + CHUNK - 1) / CHUNK)   // 118

// ---------------- workspace layout (bytes) ----------------
// boxes : BB*AA*4 f32            @ 0          size 3,840,000
// valid : BB*AA u8               @ 3,840,000  size   240,000
// hist  : BB*CC*NBINS u32        @ 4,080,000  size   163,840
// cnt   : BB*CC u32              @ 4,243,840  size       640
// cutbin: BB*CC i32              @ 4,244,480  size       640
// cand  : BB*CC*CAP u64          @ 4,245,120  size 2,621,440
// total ~6.87 MB
#define OFF_BOXES   0
#define OFF_VALID   3840000
#define OFF_HIST    4080000
#define OFF_CNT     4243840
#define OFF_CUT     4244480
#define OFF_CAND    4245120
#define ZERO_WORDS  41120   // hist + cnt contiguous, in u32 words

// ---------------- K1: decode + clip + valid, zero hist/cnt ----------------
__global__ __launch_bounds__(256) void k_decode(
    const float* __restrict__ deltas, const float* __restrict__ anchors,
    const int* __restrict__ ih, const int* __restrict__ iw,
    float* __restrict__ boxes, unsigned char* __restrict__ valid,
    unsigned int* __restrict__ zero_base)
{
    int tid = blockIdx.x * 256 + threadIdx.x;
    if (tid < ZERO_WORDS) zero_base[tid] = 0u;
    if (tid >= BB * AA) return;

    float4 d  = ((const float4*)deltas)[tid];
    float4 an = ((const float4*)anchors)[tid];

    const float CLAMPF = (float)4.135166556742356;  // float(log(1000/16))
    double W = (double)(*iw);
    double H = (double)(*ih);

    double aw  = (double)an.z - (double)an.x;
    double ah  = (double)an.w - (double)an.y;
    double acx = (double)an.x + 0.5 * aw;
    double acy = (double)an.y + 0.5 * ah;

    double dw = fmin((double)d.z, (double)CLAMPF);
    double dh = fmin((double)d.w, (double)CLAMPF);

    double pcx = (double)d.x * aw + acx;
    double pcy = (double)d.y * ah + acy;
    double pw  = exp(dw) * aw;
    double ph  = exp(dh) * ah;

    float x1 = (float)fmin(fmax(pcx - 0.5 * pw, 0.0), W);
    float y1 = (float)fmin(fmax(pcy - 0.5 * ph, 0.0), H);
    float x2 = (float)fmin(fmax(pcx + 0.5 * pw, 0.0), W);
    float y2 = (float)fmin(fmax(pcy + 0.5 * ph, 0.0), H);

    float4 bb; bb.x = x1; bb.y = y1; bb.z = x2; bb.w = y2;
    ((float4*)boxes)[tid] = bb;
    valid[tid] = (((x2 - x1) >= 0.01f) && ((y2 - y1) >= 0.01f)) ? 1 : 0;
}

// ---------------- K2: per-(b,c) score histograms ----------------
// grid: BB * NCHUNK * 2 (class halves of 40); LDS hist 40*256 u32 = 40KB
__global__ __launch_bounds__(256) void k_hist(
    const float* __restrict__ scores, const unsigned char* __restrict__ valid,
    unsigned int* __restrict__ hist)
{
    __shared__ unsigned int lh[40 * NBINS];
    __shared__ unsigned char lv[CHUNK];

    int blk  = blockIdx.x;
    int half = blk & 1;
    int ch   = (blk >> 1) % NCHUNK;
    int b    = (blk >> 1) / NCHUNK;
    int a0   = ch * CHUNK;
    int nA   = min(CHUNK, AA - a0);
    int c0   = half * 40;

    for (int i = threadIdx.x; i < 40 * NBINS; i += 256) lh[i] = 0u;
    for (int i = threadIdx.x; i < CHUNK; i += 256)
        lv[i] = (i < nA) ? valid[b * AA + a0 + i] : 0;
    __syncthreads();

    const float* sp = scores + ((size_t)(b * AA + a0)) * CC + c0;
    int total = nA * 40;
    for (int t = threadIdx.x; t < total; t += 256) {
        int al = t / 40;
        int cl = t - al * 40;
        float s = sp[(size_t)al * CC + cl];
        if (s > 0.05f && lv[al]) {
            int bin = (int)(s * 256.0f);
            bin = bin < 0 ? 0 : (bin > 255 ? 255 : bin);
            atomicAdd(&lh[cl * NBINS + bin], 1u);
        }
    }
    __syncthreads();

    unsigned int* gh = hist + ((size_t)(b * CC + c0)) * NBINS;
    for (int i = threadIdx.x; i < 40 * NBINS; i += 256) {
        unsigned int v = lh[i];
        if (v) atomicAdd(&gh[i], v);   // gh layout matches: [class_local][bin]
    }
}

// ---------------- K3: find cut bin per (b,c) ----------------
__global__ __launch_bounds__(256) void k_cut(
    const unsigned int* __restrict__ hist, int* __restrict__ cutbin)
{
    __shared__ unsigned int h[NBINS];
    __shared__ int best;
    int bc = blockIdx.x;
    int t  = threadIdx.x;
    h[t] = hist[(size_t)bc * NBINS + t];
    if (t == 0) best = 0;
    __syncthreads();
    unsigned int s = 0;
    for (int j = t; j < NBINS; ++j) s += h[j];   // suffix sum at t
    if (s >= K_PRE) atomicMax(&best, t);
    __syncthreads();
    if (t == 0) cutbin[bc] = best;
}

// ---------------- K4: gather candidates ----------------
__global__ __launch_bounds__(256) void k_gather(
    const float* __restrict__ scores, const unsigned char* __restrict__ valid,
    const int* __restrict__ cutbin, unsigned int* __restrict__ cnt,
    unsigned long long* __restrict__ cand)
{
    __shared__ unsigned char lv[CHUNK];
    __shared__ int lcut[CC];

    int blk = blockIdx.x;
    int ch  = blk % NCHUNK;
    int b   = blk / NCHUNK;
    int a0  = ch * CHUNK;
    int nA  = min(CHUNK, AA - a0);

    for (int i = threadIdx.x; i < CHUNK; i += 256)
        lv[i] = (i < nA) ? valid[b * AA + a0 + i] : 0;
    if (threadIdx.x < CC) lcut[threadIdx.x] = cutbin[b * CC + threadIdx.x];
    __syncthreads();

    const float* sp = scores + ((size_t)(b * AA + a0)) * CC;
    int total = nA * CC;
    for (int t = threadIdx.x; t < total; t += 256) {
        float s = sp[t];
        int al = t / CC;
        if (s > 0.05f && lv[al]) {
            int c = t - al * CC;
            int bin = (int)(s * 256.0f);
            bin = bin < 0 ? 0 : (bin > 255 ? 255 : bin);
            if (bin >= lcut[c]) {
                unsigned int pos = atomicAdd(&cnt[b * CC + c], 1u);
                if (pos < CAP) {
                    unsigned int a = (unsigned int)(a0 + al);
                    cand[((size_t)(b * CC + c)) * CAP + pos] =
                        (((unsigned long long)__float_as_uint(s)) << 32) |
                        (unsigned long long)(~a);
                }
            }
        }
    }
}

// ---------------- K5: sort + NMS + compact + write ----------------
__global__ __launch_bounds__(256) void k_nms(
    const float* __restrict__ boxes, const unsigned int* __restrict__ cnt,
    const unsigned long long* __restrict__ cand, float* __restrict__ out)
{
    __shared__ unsigned long long keys[CAP];        // 16 KB
    __shared__ float bx1[512], by1[512], bx2[512], by2[512], ar[512], scs[512]; // 12 KB
    __shared__ int aidx[512];                       // 2 KB
    __shared__ unsigned long long sup[512 * 8];     // 32 KB
    __shared__ unsigned long long keepsh[8];
    __shared__ int pfx[9];

    int bc = blockIdx.x;
    int b  = bc / CC;
    int n  = (int)min(cnt[bc], (unsigned int)CAP);

    const unsigned long long* cp = cand + (size_t)bc * CAP;
    for (int i = threadIdx.x; i < CAP; i += 256)
        keys[i] = (i < n) ? cp[i] : 0ull;

    // bitonic sort, descending
    for (unsigned int k = 2; k <= CAP; k <<= 1) {
        for (unsigned int j = k >> 1; j > 0; j >>= 1) {
            __syncthreads();
            for (unsigned int i = threadIdx.x; i < CAP; i += 256) {
                unsigned int ixj = i ^ j;
                if (ixj > i) {
                    unsigned long long a = keys[i], bk = keys[ixj];
                    bool up = ((i & k) == 0);
                    if (up ? (a < bk) : (a > bk)) { keys[i] = bk; keys[ixj] = a; }
                }
            }
        }
    }
    __syncthreads();

    // extract top-512, gather boxes
    for (int i = threadIdx.x; i < 512; i += 256) {
        unsigned long long key = keys[i];
        bool v = (key != 0ull);
        scs[i] = v ? __uint_as_float((unsigned int)(key >> 32)) : -1.0f;
        int a = v ? (int)(~(unsigned int)key) : 0;
        aidx[i] = a;
        float X1 = 0.f, Y1 = 0.f, X2 = 0.f, Y2 = 0.f;
        if (v && i < K_PRE) {
            float4 bb = ((const float4*)boxes)[(size_t)b * AA + a];
            X1 = bb.x; Y1 = bb.y; X2 = bb.z; Y2 = bb.w;
        }
        bx1[i] = X1; by1[i] = Y1; bx2[i] = X2; by2[i] = Y2;
        ar[i] = (X2 - X1) * (Y2 - Y1);
    }
    __syncthreads();

    // suppression bitmasks: wave per i, ballot over j
    int wave = threadIdx.x >> 6;
    int lane = threadIdx.x & 63;
    for (int i = wave; i < K_PRE; i += 4) {
        float ix1 = bx1[i], iy1 = by1[i], ix2 = bx2[i], iy2 = by2[i], ia = ar[i];
        for (int jb = 0; jb < 8; ++jb) {
            int j = jb * 64 + lane;
            bool p = false;
            if (j < K_PRE && j > i) {
                float ltx = fmaxf(ix1, bx1[j]);
                float lty = fmaxf(iy1, by1[j]);
                float rbx = fminf(ix2, bx2[j]);
                float rby = fminf(iy2, by2[j]);
                float wx = fmaxf(rbx - ltx, 0.0f);
                float wy = fmaxf(rby - lty, 0.0f);
                float inter = wx * wy;
                float iou = inter / fmaxf(ia + ar[j] - inter, 1e-9f);
                p = iou > 0.5f;
            }
            unsigned long long m = __ballot(p);
            if (lane == 0) sup[i * 8 + jb] = m;
        }
    }
    __syncthreads();

    // greedy NMS (serial over kept bits only)
    if (threadIdx.x == 0) {
        int nv = min(n, K_PRE);
        unsigned long long keep[8];
        for (int w = 0; w < 8; ++w) {
            int lo = w * 64;
            keep[w] = (nv >= lo + 64) ? ~0ull
                    : ((nv > lo) ? ((1ull << (nv - lo)) - 1ull) : 0ull);
        }
        for (int w = 0; w < 8; ++w) {
            unsigned long long m = keep[w];
            while (m) {
                int bit = __ffsll((unsigned long long)m) - 1;
                int i = w * 64 + bit;
                const unsigned long long* row = &sup[i * 8];
                keep[0] &= ~row[0]; keep[1] &= ~row[1];
                keep[2] &= ~row[2]; keep[3] &= ~row[3];
                keep[4] &= ~row[4]; keep[5] &= ~row[5];
                keep[6] &= ~row[6]; keep[7] &= ~row[7];
                m = keep[w];
                m &= (bit < 63) ? (~0ull << (bit + 1)) : 0ull;
            }
        }
        int s = 0;
        for (int w = 0; w < 8; ++w) { keepsh[w] = keep[w]; pfx[w] = s; s += __popcll(keep[w]); }
        pfx[8] = s;
    }
    __syncthreads();

    // compaction: kept first (score order), then non-kept (score order)
    int total_kept = pfx[8];
    for (int i = threadIdx.x; i < K_PRE; i += 256) {
        int w = i >> 6, bit = i & 63;
        unsigned long long kw = keepsh[w];
        bool kv = (kw >> bit) & 1ull;
        int kb = pfx[w] + __popcll(kw & ((bit == 0) ? 0ull : ((1ull << bit) - 1ull)));
        int p = kv ? kb : (total_kept + (i - kb));
        if (p < MAX_DET) {
            float* o = out + ((size_t)bc * MAX_DET + p) * 5;
            if (kv) {
                o[0] = bx1[i]; o[1] = by1[i]; o[2] = bx2[i]; o[3] = by2[i]; o[4] = scs[i];
            } else {
                o[0] = 0.f; o[1] = 0.f; o[2] = 0.f; o[3] = 0.f; o[4] = -1.0f;
            }
        }
    }
}

extern "C" void kernel_launch(void* const* d_in, const int* in_sizes, int n_in,
                              void* d_out, int out_size, void* d_ws, size_t ws_size,
                              hipStream_t stream)
{
    const float* deltas  = (const float*)d_in[0];
    const float* scores  = (const float*)d_in[1];
    const float* anchors = (const float*)d_in[2];
    const int*   ih      = (const int*)d_in[3];
    const int*   iw      = (const int*)d_in[4];
    float* out = (float*)d_out;

    char* w = (char*)d_ws;
    float*              boxes  = (float*)(w + OFF_BOXES);
    unsigned char*      valid  = (unsigned char*)(w + OFF_VALID);
    unsigned int*       hist   = (unsigned int*)(w + OFF_HIST);
    unsigned int*       cnt    = (unsigned int*)(w + OFF_CNT);
    int*                cutbin = (int*)(w + OFF_CUT);
    unsigned long long* cand   = (unsigned long long*)(w + OFF_CAND);

    int g1 = (BB * AA + 255) / 256;
    k_decode<<<g1, 256, 0, stream>>>(deltas, anchors, ih, iw, boxes, valid, hist);
    k_hist<<<BB * NCHUNK * 2, 256, 0, stream>>>(scores, valid, hist);
    k_cut<<<BB * CC, 256, 0, stream>>>(hist, cutbin);
    k_gather<<<BB * NCHUNK, 256, 0, stream>>>(scores, valid, cutbin, cnt, cand);
    k_nms<<<BB * CC, 256, 0, stream>>>(boxes, cnt, cand, out);
}

// Round 2
// 638.840 us; speedup vs baseline: 1.1565x; 1.1565x over previous
//
#include <hip/hip_runtime.h>
#include <hip/hip_bf16.h>
#include <math.h>

#define BB 2
#define AA 120000
#define CC 80
#define K_PRE 500
#define MAX_DET 300
#define CAP 2048
#define NBINS 128
#define NCH 30                    // anchor chunks for hist/gather
#define CHUNKA ((AA + NCH - 1) / NCH)   // 4000

// ---------------- workspace layout (bytes) ----------------
// boxes : BB*AA*4 f32            @ 0          3,840,000
// valid : BB*AA u8               @ 3,840,000    240,000
// hist  : BB*CC*NBINS u32        @ 4,080,000     81,920
// cnt   : BB*CC u32              @ 4,161,920        640
// cutbin: BB*CC i32              @ 4,162,560        640
// cand  : BB*CC*CAP u64          @ 4,163,200  2,621,440
#define OFF_BOXES   0
#define OFF_VALID   3840000
#define OFF_HIST    4080000
#define OFF_CNT     4161920
#define OFF_CUT     4162560
#define OFF_CAND    4163200
#define ZERO_WORDS  20640   // hist + cnt contiguous, in u32 words

// ---------------- K1: decode + clip + valid, zero hist/cnt ----------------
__global__ __launch_bounds__(256) void k_decode(
    const float* __restrict__ deltas, const float* __restrict__ anchors,
    const int* __restrict__ ih, const int* __restrict__ iw,
    float* __restrict__ boxes, unsigned char* __restrict__ valid,
    unsigned int* __restrict__ zero_base)
{
    int tid = blockIdx.x * 256 + threadIdx.x;
    if (tid < ZERO_WORDS) zero_base[tid] = 0u;
    if (tid >= BB * AA) return;

    float4 d  = ((const float4*)deltas)[tid];
    float4 an = ((const float4*)anchors)[tid];

    const float CLAMPF = (float)4.135166556742356;  // float(log(1000/16))
    double W = (double)(*iw);
    double H = (double)(*ih);

    double aw  = (double)an.z - (double)an.x;
    double ah  = (double)an.w - (double)an.y;
    double acx = (double)an.x + 0.5 * aw;
    double acy = (double)an.y + 0.5 * ah;

    double dw = fmin((double)d.z, (double)CLAMPF);
    double dh = fmin((double)d.w, (double)CLAMPF);

    double pcx = (double)d.x * aw + acx;
    double pcy = (double)d.y * ah + acy;
    double pw  = exp(dw) * aw;
    double ph  = exp(dh) * ah;

    float x1 = (float)fmin(fmax(pcx - 0.5 * pw, 0.0), W);
    float y1 = (float)fmin(fmax(pcy - 0.5 * ph, 0.0), H);
    float x2 = (float)fmin(fmax(pcx + 0.5 * pw, 0.0), W);
    float y2 = (float)fmin(fmax(pcy + 0.5 * ph, 0.0), H);

    float4 bb; bb.x = x1; bb.y = y1; bb.z = x2; bb.w = y2;
    ((float4*)boxes)[tid] = bb;
    valid[tid] = (((x2 - x1) >= 0.01f) && ((y2 - y1) >= 0.01f)) ? 1 : 0;
}

// ---------------- K2: per-(b,c) score histograms ----------------
// block = (b, class-quad q, anchor-chunk). One float4/anchor, 4 classes.
// LDS hist 4*128 u32 = 2 KB. grid = BB*20*NCH = 1200 blocks.
__global__ __launch_bounds__(256) void k_hist(
    const float* __restrict__ scores, const unsigned char* __restrict__ valid,
    unsigned int* __restrict__ hist)
{
    __shared__ unsigned int lh[4 * NBINS];

    int blk = blockIdx.x;
    int ch  = blk % NCH;
    int q   = (blk / NCH) % 20;
    int b   = blk / (NCH * 20);
    int a0  = ch * CHUNKA;
    int a1  = min(a0 + CHUNKA, AA);

    for (int i = threadIdx.x; i < 4 * NBINS; i += 256) lh[i] = 0u;
    __syncthreads();

    const float4* s4 = (const float4*)scores;
    for (int a = a0 + threadIdx.x; a < a1; a += 256) {
        int ga = b * AA + a;
        float4 s = s4[(size_t)ga * 20 + q];
        bool v = valid[ga] != 0;
        if (v) {
            if (s.x > 0.05f) { int bn = min((int)(s.x * (float)NBINS), NBINS - 1); atomicAdd(&lh[0 * NBINS + bn], 1u); }
            if (s.y > 0.05f) { int bn = min((int)(s.y * (float)NBINS), NBINS - 1); atomicAdd(&lh[1 * NBINS + bn], 1u); }
            if (s.z > 0.05f) { int bn = min((int)(s.z * (float)NBINS), NBINS - 1); atomicAdd(&lh[2 * NBINS + bn], 1u); }
            if (s.w > 0.05f) { int bn = min((int)(s.w * (float)NBINS), NBINS - 1); atomicAdd(&lh[3 * NBINS + bn], 1u); }
        }
    }
    __syncthreads();

    unsigned int* gh = hist + ((size_t)(b * CC + 4 * q)) * NBINS;
    for (int i = threadIdx.x; i < 4 * NBINS; i += 256) {
        unsigned int vv = lh[i];
        if (vv) atomicAdd(&gh[i], vv);
    }
}

// ---------------- K3: find cut bin per (b,c) ----------------
__global__ __launch_bounds__(128) void k_cut(
    const unsigned int* __restrict__ hist, int* __restrict__ cutbin)
{
    __shared__ unsigned int h[NBINS];
    __shared__ int best;
    int bc = blockIdx.x;
    int t  = threadIdx.x;
    h[t] = hist[(size_t)bc * NBINS + t];
    if (t == 0) best = 0;
    __syncthreads();
    unsigned int s = 0;
    for (int j = t; j < NBINS; ++j) s += h[j];   // suffix sum at t
    if (s >= K_PRE) atomicMax(&best, t);
    __syncthreads();
    if (t == 0) cutbin[bc] = best;
}

// ---------------- K4: gather candidates ----------------
// same block structure as k_hist
__global__ __launch_bounds__(256) void k_gather(
    const float* __restrict__ scores, const unsigned char* __restrict__ valid,
    const int* __restrict__ cutbin, unsigned int* __restrict__ cnt,
    unsigned long long* __restrict__ cand)
{
    int blk = blockIdx.x;
    int ch  = blk % NCH;
    int q   = (blk / NCH) % 20;
    int b   = blk / (NCH * 20);
    int a0  = ch * CHUNKA;
    int a1  = min(a0 + CHUNKA, AA);

    int cbase = b * CC + 4 * q;
    int cut0 = cutbin[cbase + 0];
    int cut1 = cutbin[cbase + 1];
    int cut2 = cutbin[cbase + 2];
    int cut3 = cutbin[cbase + 3];

    const float4* s4 = (const float4*)scores;
    for (int a = a0 + threadIdx.x; a < a1; a += 256) {
        int ga = b * AA + a;
        float4 s = s4[(size_t)ga * 20 + q];
        bool v = valid[ga] != 0;
        if (v) {
            unsigned long long lokey = (unsigned long long)(~(unsigned int)a);
            #define EMIT(comp, cut, cl)                                               \
                if (comp > 0.05f) {                                                   \
                    int bn = min((int)(comp * (float)NBINS), NBINS - 1);              \
                    if (bn >= cut) {                                                  \
                        unsigned int pos = atomicAdd(&cnt[cbase + cl], 1u);           \
                        if (pos < CAP)                                                \
                            cand[((size_t)(cbase + cl)) * CAP + pos] =                \
                                (((unsigned long long)__float_as_uint(comp)) << 32) | lokey; \
                    }                                                                 \
                }
            EMIT(s.x, cut0, 0)
            EMIT(s.y, cut1, 1)
            EMIT(s.z, cut2, 2)
            EMIT(s.w, cut3, 3)
            #undef EMIT
        }
    }
}

// ---------------- K5: sort + NMS + compact + write ----------------
__global__ __launch_bounds__(256) void k_nms(
    const float* __restrict__ boxes, const unsigned int* __restrict__ cnt,
    const unsigned long long* __restrict__ cand, float* __restrict__ out)
{
    __shared__ unsigned long long keys[CAP];        // 16 KB
    __shared__ float bx1[512], by1[512], bx2[512], by2[512], ar[512], scs[512]; // 12 KB
    __shared__ unsigned long long sup[512 * 8];     // 32 KB
    __shared__ unsigned long long keepsh[8];
    __shared__ int pfx[9];

    int bc = blockIdx.x;
    int b  = bc / CC;
    int n  = (int)min(cnt[bc], (unsigned int)CAP);

    const unsigned long long* cp = cand + (size_t)bc * CAP;
    for (int i = threadIdx.x; i < CAP; i += 256)
        keys[i] = (i < n) ? cp[i] : 0ull;

    // bitonic sort, descending
    for (unsigned int k = 2; k <= CAP; k <<= 1) {
        for (unsigned int j = k >> 1; j > 0; j >>= 1) {
            __syncthreads();
            for (unsigned int i = threadIdx.x; i < CAP; i += 256) {
                unsigned int ixj = i ^ j;
                if (ixj > i) {
                    unsigned long long a = keys[i], bk = keys[ixj];
                    bool up = ((i & k) == 0);
                    if (up ? (a < bk) : (a > bk)) { keys[i] = bk; keys[ixj] = a; }
                }
            }
        }
    }
    __syncthreads();

    // extract top-512, gather boxes
    for (int i = threadIdx.x; i < 512; i += 256) {
        unsigned long long key = keys[i];
        bool v = (key != 0ull);
        scs[i] = v ? __uint_as_float((unsigned int)(key >> 32)) : -1.0f;
        int a = v ? (int)(~(unsigned int)key) : 0;
        float X1 = 0.f, Y1 = 0.f, X2 = 0.f, Y2 = 0.f;
        if (v && i < K_PRE) {
            float4 bb = ((const float4*)boxes)[(size_t)b * AA + a];
            X1 = bb.x; Y1 = bb.y; X2 = bb.z; Y2 = bb.w;
        }
        bx1[i] = X1; by1[i] = Y1; bx2[i] = X2; by2[i] = Y2;
        ar[i] = (X2 - X1) * (Y2 - Y1);
    }
    __syncthreads();

    // suppression bitmasks: wave per i, ballot over j
    int wave = threadIdx.x >> 6;
    int lane = threadIdx.x & 63;
    for (int i = wave; i < K_PRE; i += 4) {
        float ix1 = bx1[i], iy1 = by1[i], ix2 = bx2[i], iy2 = by2[i], ia = ar[i];
        for (int jb = 0; jb < 8; ++jb) {
            int j = jb * 64 + lane;
            bool p = false;
            if (j < K_PRE && j > i) {
                float ltx = fmaxf(ix1, bx1[j]);
                float lty = fmaxf(iy1, by1[j]);
                float rbx = fminf(ix2, bx2[j]);
                float rby = fminf(iy2, by2[j]);
                float wx = fmaxf(rbx - ltx, 0.0f);
                float wy = fmaxf(rby - lty, 0.0f);
                float inter = wx * wy;
                float iou = inter / fmaxf(ia + ar[j] - inter, 1e-9f);
                p = iou > 0.5f;
            }
            unsigned long long m = __ballot(p);
            if (lane == 0) sup[i * 8 + jb] = m;
        }
    }
    __syncthreads();

    // greedy NMS (serial over kept bits only)
    if (threadIdx.x == 0) {
        int nv = min(n, K_PRE);
        unsigned long long keep[8];
        for (int w = 0; w < 8; ++w) {
            int lo = w * 64;
            keep[w] = (nv >= lo + 64) ? ~0ull
                    : ((nv > lo) ? ((1ull << (nv - lo)) - 1ull) : 0ull);
        }
        for (int w = 0; w < 8; ++w) {
            unsigned long long m = keep[w];
            while (m) {
                int bit = __ffsll((unsigned long long)m) - 1;
                int i = w * 64 + bit;
                const unsigned long long* row = &sup[i * 8];
                keep[0] &= ~row[0]; keep[1] &= ~row[1];
                keep[2] &= ~row[2]; keep[3] &= ~row[3];
                keep[4] &= ~row[4]; keep[5] &= ~row[5];
                keep[6] &= ~row[6]; keep[7] &= ~row[7];
                m = keep[w];
                m &= (bit < 63) ? (~0ull << (bit + 1)) : 0ull;
            }
        }
        int s = 0;
        for (int w = 0; w < 8; ++w) { keepsh[w] = keep[w]; pfx[w] = s; s += __popcll(keep[w]); }
        pfx[8] = s;
    }
    __syncthreads();

    // compaction: kept first (score order), then non-kept (score order)
    int total_kept = pfx[8];
    for (int i = threadIdx.x; i < K_PRE; i += 256) {
        int w = i >> 6, bit = i & 63;
        unsigned long long kw = keepsh[w];
        bool kv = (kw >> bit) & 1ull;
        int kb = pfx[w] + __popcll(kw & ((bit == 0) ? 0ull : ((1ull << bit) - 1ull)));
        int p = kv ? kb : (total_kept + (i - kb));
        if (p < MAX_DET) {
            float* o = out + ((size_t)bc * MAX_DET + p) * 5;
            if (kv) {
                o[0] = bx1[i]; o[1] = by1[i]; o[2] = bx2[i]; o[3] = by2[i]; o[4] = scs[i];
            } else {
                o[0] = 0.f; o[1] = 0.f; o[2] = 0.f; o[3] = 0.f; o[4] = -1.0f;
            }
        }
    }
}

extern "C" void kernel_launch(void* const* d_in, const int* in_sizes, int n_in,
                              void* d_out, int out_size, void* d_ws, size_t ws_size,
                              hipStream_t stream)
{
    const float* deltas  = (const float*)d_in[0];
    const float* scores  = (const float*)d_in[1];
    const float* anchors = (const float*)d_in[2];
    const int*   ih      = (const int*)d_in[3];
    const int*   iw      = (const int*)d_in[4];
    float* out = (float*)d_out;

    char* w = (char*)d_ws;
    float*              boxes  = (float*)(w + OFF_BOXES);
    unsigned char*      valid  = (unsigned char*)(w + OFF_VALID);
    unsigned int*       hist   = (unsigned int*)(w + OFF_HIST);
    unsigned int*       cnt    = (unsigned int*)(w + OFF_CNT);
    int*                cutbin = (int*)(w + OFF_CUT);
    unsigned long long* cand   = (unsigned long long*)(w + OFF_CAND);

    int g1 = (BB * AA + 255) / 256;
    k_decode<<<g1, 256, 0, stream>>>(deltas, anchors, ih, iw, boxes, valid, hist);
    k_hist<<<BB * 20 * NCH, 256, 0, stream>>>(scores, valid, hist);
    k_cut<<<BB * CC, 128, 0, stream>>>(hist, cutbin);
    k_gather<<<BB * 20 * NCH, 256, 0, stream>>>(scores, valid, cutbin, cnt, cand);
    k_nms<<<BB * CC, 256, 0, stream>>>(boxes, cnt, cand, out);
}

// Round 4
// 559.960 us; speedup vs baseline: 1.3194x; 1.1409x over previous
//
#include <hip/hip_runtime.h>
#include <hip/hip_bf16.h>
#include <math.h>

#define BB 2
#define AA 120000
#define CC 80
#define K_PRE 500
#define MAX_DET 300
#define CAP 2048
#define NBINS 256
#define NCH 30                    // anchor chunks for hist/gather
#define CHUNKA ((AA + NCH - 1) / NCH)   // 4000

// ---------------- workspace layout (bytes) ----------------
// boxes : BB*AA*4 f32            @ 0          3,840,000
// valid : BB*AA u8               @ 3,840,000    240,000
// hist  : BB*CC*NBINS u32        @ 4,080,000    163,840
// cnt   : BB*CC u32              @ 4,243,840        640
// cutbin: BB*CC i32              @ 4,244,480        640
// cand  : BB*CC*CAP u64          @ 4,245,120  2,621,440
#define OFF_BOXES   0
#define OFF_VALID   3840000
#define OFF_HIST    4080000
#define OFF_CNT     4243840
#define OFF_CUT     4244480
#define OFF_CAND    4245120
#define ZERO_WORDS  41120   // hist + cnt contiguous, in u32 words

// ---------------- K1: decode + clip + valid, zero hist/cnt ----------------
__global__ __launch_bounds__(256) void k_decode(
    const float* __restrict__ deltas, const float* __restrict__ anchors,
    const int* __restrict__ ih, const int* __restrict__ iw,
    float* __restrict__ boxes, unsigned char* __restrict__ valid,
    unsigned int* __restrict__ zero_base)
{
    int tid = blockIdx.x * 256 + threadIdx.x;
    if (tid < ZERO_WORDS) zero_base[tid] = 0u;
    if (tid >= BB * AA) return;

    float4 d  = ((const float4*)deltas)[tid];
    float4 an = ((const float4*)anchors)[tid];

    const float CLAMPF = (float)4.135166556742356;  // float(log(1000/16))
    double W = (double)(*iw);
    double H = (double)(*ih);

    double aw  = (double)an.z - (double)an.x;
    double ah  = (double)an.w - (double)an.y;
    double acx = (double)an.x + 0.5 * aw;
    double acy = (double)an.y + 0.5 * ah;

    double dw = fmin((double)d.z, (double)CLAMPF);
    double dh = fmin((double)d.w, (double)CLAMPF);

    double pcx = (double)d.x * aw + acx;
    double pcy = (double)d.y * ah + acy;
    double pw  = exp(dw) * aw;
    double ph  = exp(dh) * ah;

    float x1 = (float)fmin(fmax(pcx - 0.5 * pw, 0.0), W);
    float y1 = (float)fmin(fmax(pcy - 0.5 * ph, 0.0), H);
    float x2 = (float)fmin(fmax(pcx + 0.5 * pw, 0.0), W);
    float y2 = (float)fmin(fmax(pcy + 0.5 * ph, 0.0), H);

    float4 bb; bb.x = x1; bb.y = y1; bb.z = x2; bb.w = y2;
    ((float4*)boxes)[tid] = bb;
    valid[tid] = (((x2 - x1) >= 0.01f) && ((y2 - y1) >= 0.01f)) ? 1 : 0;
}

// ---------------- K2: per-(b,c) score histograms ----------------
// block = (b, class-quad q, anchor-chunk). One float4/anchor, 4 classes.
// LDS hist 4*256 u32 = 4 KB. grid = BB*20*NCH = 1200 blocks.
__global__ __launch_bounds__(256) void k_hist(
    const float* __restrict__ scores, const unsigned char* __restrict__ valid,
    unsigned int* __restrict__ hist)
{
    __shared__ unsigned int lh[4 * NBINS];

    int blk = blockIdx.x;
    int ch  = blk % NCH;
    int q   = (blk / NCH) % 20;
    int b   = blk / (NCH * 20);
    int a0  = ch * CHUNKA;
    int a1  = min(a0 + CHUNKA, AA);

    for (int i = threadIdx.x; i < 4 * NBINS; i += 256) lh[i] = 0u;
    __syncthreads();

    const float4* s4 = (const float4*)scores;
    for (int a = a0 + threadIdx.x; a < a1; a += 256) {
        int ga = b * AA + a;
        float4 s = s4[(size_t)ga * 20 + q];
        bool v = valid[ga] != 0;
        if (v) {
            if (s.x > 0.05f) { int bn = min((int)(s.x * (float)NBINS), NBINS - 1); atomicAdd(&lh[0 * NBINS + bn], 1u); }
            if (s.y > 0.05f) { int bn = min((int)(s.y * (float)NBINS), NBINS - 1); atomicAdd(&lh[1 * NBINS + bn], 1u); }
            if (s.z > 0.05f) { int bn = min((int)(s.z * (float)NBINS), NBINS - 1); atomicAdd(&lh[2 * NBINS + bn], 1u); }
            if (s.w > 0.05f) { int bn = min((int)(s.w * (float)NBINS), NBINS - 1); atomicAdd(&lh[3 * NBINS + bn], 1u); }
        }
    }
    __syncthreads();

    unsigned int* gh = hist + ((size_t)(b * CC + 4 * q)) * NBINS;
    for (int i = threadIdx.x; i < 4 * NBINS; i += 256) {
        unsigned int vv = lh[i];
        if (vv) atomicAdd(&gh[i], vv);
    }
}

// ---------------- K3: find cut bin per (b,c) ----------------
__global__ __launch_bounds__(256) void k_cut(
    const unsigned int* __restrict__ hist, int* __restrict__ cutbin)
{
    __shared__ unsigned int h[NBINS];
    __shared__ int best;
    int bc = blockIdx.x;
    int t  = threadIdx.x;
    h[t] = hist[(size_t)bc * NBINS + t];
    if (t == 0) best = 0;
    __syncthreads();
    unsigned int s = 0;
    for (int j = t; j < NBINS; ++j) s += h[j];   // suffix sum at t
    if (s >= K_PRE) atomicMax(&best, t);
    __syncthreads();
    if (t == 0) cutbin[bc] = best;
}

// ---------------- K4: gather candidates ----------------
// same block structure as k_hist
__global__ __launch_bounds__(256) void k_gather(
    const float* __restrict__ scores, const unsigned char* __restrict__ valid,
    const int* __restrict__ cutbin, unsigned int* __restrict__ cnt,
    unsigned long long* __restrict__ cand)
{
    int blk = blockIdx.x;
    int ch  = blk % NCH;
    int q   = (blk / NCH) % 20;
    int b   = blk / (NCH * 20);
    int a0  = ch * CHUNKA;
    int a1  = min(a0 + CHUNKA, AA);

    int cbase = b * CC + 4 * q;
    int cut0 = cutbin[cbase + 0];
    int cut1 = cutbin[cbase + 1];
    int cut2 = cutbin[cbase + 2];
    int cut3 = cutbin[cbase + 3];

    const float4* s4 = (const float4*)scores;
    for (int a = a0 + threadIdx.x; a < a1; a += 256) {
        int ga = b * AA + a;
        float4 s = s4[(size_t)ga * 20 + q];
        bool v = valid[ga] != 0;
        if (v) {
            unsigned long long lokey = (unsigned long long)(~(unsigned int)a);
            #define EMIT(comp, cut, cl)                                               \
                if (comp > 0.05f) {                                                   \
                    int bn = min((int)(comp * (float)NBINS), NBINS - 1);              \
                    if (bn >= cut) {                                                  \
                        unsigned int pos = atomicAdd(&cnt[cbase + cl], 1u);           \
                        if (pos < CAP)                                                \
                            cand[((size_t)(cbase + cl)) * CAP + pos] =                \
                                (((unsigned long long)__float_as_uint(comp)) << 32) | lokey; \
                    }                                                                 \
                }
            EMIT(s.x, cut0, 0)
            EMIT(s.y, cut1, 1)
            EMIT(s.z, cut2, 2)
            EMIT(s.w, cut3, 3)
            #undef EMIT
        }
    }
}

// ---------------- K5: sort + NMS + compact + write ----------------
// 1024 threads (16 waves). LDS ~60 KB.
// NOTE: sup[i*8 + w] is only WRITTEN for w >= (i>>6) (triangular skip in the
// mask phase). All readers MUST treat w < (i>>6) as zero — those bits are
// j < i and sup rows only suppress j > i.
__global__ __launch_bounds__(1024) void k_nms(
    const float* __restrict__ boxes, const unsigned int* __restrict__ cnt,
    const unsigned long long* __restrict__ cand, float* __restrict__ out)
{
    __shared__ unsigned long long keys[CAP];        // 16 KB
    __shared__ float4 box4[512];                    // 8 KB
    __shared__ float ar[512], scs[512];             // 4 KB
    __shared__ unsigned long long sup[512 * 8];     // 32 KB
    __shared__ unsigned long long keepsh[8];
    __shared__ int pfx[9];

    int bc = blockIdx.x;
    int b  = bc / CC;
    int n  = (int)min(cnt[bc], (unsigned int)CAP);
    int SS = (n > 1024) ? 2048 : 1024;              // adaptive sort size

    const unsigned long long* cp = cand + (size_t)bc * CAP;
    for (int i = threadIdx.x; i < SS; i += 1024)
        keys[i] = (i < n) ? cp[i] : 0ull;

    // bitonic sort, descending
    for (unsigned int k = 2; k <= (unsigned int)SS; k <<= 1) {
        for (unsigned int j = k >> 1; j > 0; j >>= 1) {
            __syncthreads();
            for (unsigned int i = threadIdx.x; i < (unsigned int)SS; i += 1024) {
                unsigned int ixj = i ^ j;
                if (ixj > i) {
                    unsigned long long a = keys[i], bk = keys[ixj];
                    bool up = ((i & k) == 0);
                    if (up ? (a < bk) : (a > bk)) { keys[i] = bk; keys[ixj] = a; }
                }
            }
        }
    }
    __syncthreads();

    // extract top-512, gather boxes
    if (threadIdx.x < 512) {
        int i = threadIdx.x;
        unsigned long long key = keys[i];
        bool v = (key != 0ull);
        scs[i] = v ? __uint_as_float((unsigned int)(key >> 32)) : -1.0f;
        int a = v ? (int)(~(unsigned int)key) : 0;
        float4 bb = make_float4(0.f, 0.f, 0.f, 0.f);
        if (v && i < K_PRE) bb = ((const float4*)boxes)[(size_t)b * AA + a];
        box4[i] = bb;
        ar[i] = (bb.z - bb.x) * (bb.w - bb.y);
    }
    __syncthreads();

    // suppression bitmasks: wave per i (16 waves), ballot over j; triangular skip
    {
        int wave = threadIdx.x >> 6;
        int lane = threadIdx.x & 63;
        for (int i = wave; i < K_PRE; i += 16) {
            float4 bi = box4[i];
            float ia = ar[i];
            for (int jb = (i >> 6); jb < 8; ++jb) {
                int j = jb * 64 + lane;
                bool p = false;
                if (j < K_PRE && j > i) {
                    float4 bj = box4[j];
                    float ltx = fmaxf(bi.x, bj.x);
                    float lty = fmaxf(bi.y, bj.y);
                    float rbx = fminf(bi.z, bj.z);
                    float rby = fminf(bi.w, bj.w);
                    float wx = fmaxf(rbx - ltx, 0.0f);
                    float wy = fmaxf(rby - lty, 0.0f);
                    float inter = wx * wy;
                    float iou = inter / fmaxf(ia + ar[j] - inter, 1e-9f);
                    p = iou > 0.5f;
                }
                unsigned long long m = __ballot(p);
                if (lane == 0) sup[i * 8 + jb] = m;
            }
        }
    }
    __syncthreads();

    // greedy NMS: wave 0, lanes 0-7 own keep words; speculative row prefetch.
    // Row reads are masked: word `lane` of row i is only valid for
    // lane >= (i>>6) (triangular sup fill); below that it's garbage -> use 0.
    if (threadIdx.x < 64) {
        int lane = threadIdx.x;
        bool owner = lane < 8;
        int nv = min(n, K_PRE);
        unsigned long long word = 0ull;
        if (owner) {
            int lo = lane << 6;
            word = (nv >= lo + 64) ? ~0ull
                 : ((nv > lo) ? ((1ull << (nv - lo)) - 1ull) : 0ull);
        }
        unsigned long long sword = word;   // search mask (bits ≤ current cleared)

        #define FINDNEXT(dst)                                                        \
            {                                                                        \
                int c_ = (owner && sword) ? ((lane << 6) + __ffsll((long long)sword) - 1) : 4096; \
                c_ = min(c_, __shfl_xor(c_, 4));                                     \
                c_ = min(c_, __shfl_xor(c_, 2));                                     \
                c_ = min(c_, __shfl_xor(c_, 1));                                     \
                dst = __shfl(c_, 0);                                                 \
            }
        #define CLEAR_LE(ii)                                                         \
            if (lane == ((ii) >> 6)) sword &= ~((2ull << ((ii) & 63)) - 1ull);
        #define ROWLOAD(ii) ((owner && lane >= ((ii) >> 6)) ? sup[((ii) << 3) + lane] : 0ull)

        int i1; FINDNEXT(i1);
        unsigned long long row1 = 0ull;
        if (i1 < 4096) { CLEAR_LE(i1); row1 = ROWLOAD(i1); }
        while (i1 < 4096) {
            int i2; FINDNEXT(i2);                 // speculative: before row1 applied
            unsigned long long row2 = (i2 < 4096) ? ROWLOAD(i2) : 0ull;
            if (owner) { word &= ~row1; sword &= ~row1; }
            if (i2 < 4096) {
                int bitv = (int)((sword >> (i2 & 63)) & 1ull);
                int alive = __shfl(bitv, i2 >> 6);
                if (alive) { CLEAR_LE(i2); i1 = i2; row1 = row2; continue; }
            }
            FINDNEXT(i1);
            row1 = 0ull;
            if (i1 < 4096) { CLEAR_LE(i1); row1 = ROWLOAD(i1); }
        }
        if (owner) keepsh[lane] = word;
        #undef FINDNEXT
        #undef CLEAR_LE
        #undef ROWLOAD
    }
    __syncthreads();

    if (threadIdx.x == 0) {
        int s = 0;
        for (int w = 0; w < 8; ++w) { pfx[w] = s; s += __popcll(keepsh[w]); }
        pfx[8] = s;
    }
    __syncthreads();

    // compaction: kept first (score order), then non-kept (score order)
    int total_kept = pfx[8];
    if (threadIdx.x < K_PRE) {
        int i = threadIdx.x;
        int w = i >> 6, bit = i & 63;
        unsigned long long kw = keepsh[w];
        bool kv = (kw >> bit) & 1ull;
        int kb = pfx[w] + __popcll(kw & ((bit == 0) ? 0ull : ((1ull << bit) - 1ull)));
        int p = kv ? kb : (total_kept + (i - kb));
        if (p < MAX_DET) {
            float* o = out + ((size_t)bc * MAX_DET + p) * 5;
            if (kv) {
                float4 bb = box4[i];
                o[0] = bb.x; o[1] = bb.y; o[2] = bb.z; o[3] = bb.w; o[4] = scs[i];
            } else {
                o[0] = 0.f; o[1] = 0.f; o[2] = 0.f; o[3] = 0.f; o[4] = -1.0f;
            }
        }
    }
}

extern "C" void kernel_launch(void* const* d_in, const int* in_sizes, int n_in,
                              void* d_out, int out_size, void* d_ws, size_t ws_size,
                              hipStream_t stream)
{
    const float* deltas  = (const float*)d_in[0];
    const float* scores  = (const float*)d_in[1];
    const float* anchors = (const float*)d_in[2];
    const int*   ih      = (const int*)d_in[3];
    const int*   iw      = (const int*)d_in[4];
    float* out = (float*)d_out;

    char* w = (char*)d_ws;
    float*              boxes  = (float*)(w + OFF_BOXES);
    unsigned char*      valid  = (unsigned char*)(w + OFF_VALID);
    unsigned int*       hist   = (unsigned int*)(w + OFF_HIST);
    unsigned int*       cnt    = (unsigned int*)(w + OFF_CNT);
    int*                cutbin = (int*)(w + OFF_CUT);
    unsigned long long* cand   = (unsigned long long*)(w + OFF_CAND);

    int g1 = (BB * AA + 255) / 256;
    k_decode<<<g1, 256, 0, stream>>>(deltas, anchors, ih, iw, boxes, valid, hist);
    k_hist<<<BB * 20 * NCH, 256, 0, stream>>>(scores, valid, hist);
    k_cut<<<BB * CC, NBINS, 0, stream>>>(hist, cutbin);
    k_gather<<<BB * 20 * NCH, 256, 0, stream>>>(scores, valid, cutbin, cnt, cand);
    k_nms<<<BB * CC, 1024, 0, stream>>>(boxes, cnt, cand, out);
}